// Round 6
// baseline (165.040 us; speedup 1.0000x reference)
//
#include <hip/hip_runtime.h>
#include <math.h>

// HadamardProj: out[b,o] = -scale * (x[b]/(||x[b]||+eps)) . H[o,:] + bias[o]
// H[o,i] = (-1)^popcount(o&i), i<2048  =>  H row o == H row (o mod 2048)
// => y[b] = FWHT_2048(x[b]) (Sylvester), out[b,o] = -scale*inv_norm*y[o&2047] + bias[o]
//
// R6: FWHT identical to R5 (register-resident, lane owns e = j*256+lane*4+c).
// Epilogue restructured: y staged in LDS, then the BLOCK writes its whole
// 160,000-B output span in address order (256 threads x 4 KB per iteration,
// fill-kernel pattern) instead of 4 independent per-wave row streams.

typedef float f32x4 __attribute__((ext_vector_type(4)));

constexpr int N_IN  = 2048;    // 2^11
constexpr int N_OUT = 10000;
constexpr int ROWS_PER_BLOCK = 4;  // one wave64 per row

__global__ __launch_bounds__(256, 4) void fwht_proj_kernel(
    const float* __restrict__ x,
    const float* __restrict__ scale,
    const float* __restrict__ bias,
    float* __restrict__ out)
{
    __shared__ float ylds[ROWS_PER_BLOCK * N_IN];   // 32 KiB
    __shared__ float slds[ROWS_PER_BLOCK];          // per-row -scale*inv_norm

    const int wave = threadIdx.x >> 6;
    const int lane = threadIdx.x & 63;
    const int row  = (blockIdx.x << 2) + wave;     // rows % 4 == 0

    const float* __restrict__ xrow = x + (size_t)row * N_IN;

    // Vector loads: lane reads f32x4 at j*256 + lane*4  (1 KiB/instr, coalesced)
    f32x4 v[8];
    float ss = 0.0f;
#pragma unroll
    for (int j = 0; j < 8; ++j) {
        v[j] = *reinterpret_cast<const f32x4*>(xrow + (j << 8) + (lane << 2));
        ss = fmaf(v[j].x, v[j].x, ss);
        ss = fmaf(v[j].y, v[j].y, ss);
        ss = fmaf(v[j].z, v[j].z, ss);
        ss = fmaf(v[j].w, v[j].w, ss);
    }
#pragma unroll
    for (int m = 1; m < 64; m <<= 1)
        ss += __shfl_xor(ss, m, 64);
    const float inv = 1.0f / (sqrtf(ss) + 1e-8f);  // matches x/(norm+eps)

    // Stages h=1, h=2: inside each float4
#pragma unroll
    for (int j = 0; j < 8; ++j) {
        const f32x4 a = v[j];
        f32x4 t;
        t.x = a.x + a.y;  t.y = a.x - a.y;
        t.z = a.z + a.w;  t.w = a.z - a.w;
        f32x4 u;
        u.x = t.x + t.z;  u.y = t.y + t.w;
        u.z = t.x - t.z;  u.w = t.y - t.w;
        v[j] = u;
    }
    // Stages h=4..128: cross-lane, lane xor mask m = h/4 = 1..32
#pragma unroll
    for (int m = 1; m <= 32; m <<= 1) {
        const bool lo = (lane & m) == 0;
#pragma unroll
        for (int j = 0; j < 8; ++j) {
            f32x4 o;
            o.x = __shfl_xor(v[j].x, m, 64);
            o.y = __shfl_xor(v[j].y, m, 64);
            o.z = __shfl_xor(v[j].z, m, 64);
            o.w = __shfl_xor(v[j].w, m, 64);
            v[j] = lo ? (v[j] + o) : (o - v[j]);
        }
    }
    // Stages h=256,512,1024: register index xor 1,2,4
#pragma unroll
    for (int jm = 1; jm <= 4; jm <<= 1) {
#pragma unroll
        for (int j = 0; j < 8; ++j) {
            if ((j & jm) == 0) {
                const f32x4 a = v[j], b = v[j ^ jm];
                v[j]      = a + b;
                v[j ^ jm] = a - b;
            }
        }
    }

    // Stage y + per-row coefficient into LDS
    const float s = -scale[0] * inv;
    if (lane == 0) slds[wave] = s;
#pragma unroll
    for (int j = 0; j < 8; ++j)
        *reinterpret_cast<f32x4*>(&ylds[(wave << 11) + (j << 8) + (lane << 2)]) = v[j];

    __syncthreads();

    // Block-linear epilogue: block writes out[block*40000 .. +39999] in address
    // order; per iteration 256 threads store 4 KB contiguous (fill pattern).
    float* __restrict__ oblk = out + (size_t)blockIdx.x * (ROWS_PER_BLOCK * N_OUT);
    const int tid = threadIdx.x;
#pragma unroll 4
    for (int it = 0; it < 39; ++it) {
        const int gf = (it << 10) + (tid << 2);   // float offset, 4-aligned
        const int r  = (gf >= 30000) ? 3 : (gf >= 20000) ? 2 : (gf >= 10000) ? 1 : 0;
        const int o  = gf - r * 10000;            // 0..9996, 4-aligned
        const f32x4 y = *reinterpret_cast<const f32x4*>(&ylds[(r << 11) + (o & (N_IN - 1))]);
        const f32x4 b = *reinterpret_cast<const f32x4*>(bias + o);
        const float sr = slds[r];
        f32x4 rv;
        rv.x = fmaf(sr, y.x, b.x);
        rv.y = fmaf(sr, y.y, b.y);
        rv.z = fmaf(sr, y.z, b.z);
        rv.w = fmaf(sr, y.w, b.w);
        *reinterpret_cast<f32x4*>(oblk + gf) = rv;
    }
    // Tail: 40000 - 39*1024 = 64 floats, threads 0..15
    if (tid < 16) {
        const int gf = 39936 + (tid << 2);
        const int o  = gf - 30000;                // row 3: 9936..9996
        const f32x4 y = *reinterpret_cast<const f32x4*>(&ylds[(3 << 11) + (o & (N_IN - 1))]);
        const f32x4 b = *reinterpret_cast<const f32x4*>(bias + o);
        const float sr = slds[3];
        f32x4 rv;
        rv.x = fmaf(sr, y.x, b.x);
        rv.y = fmaf(sr, y.y, b.y);
        rv.z = fmaf(sr, y.z, b.z);
        rv.w = fmaf(sr, y.w, b.w);
        *reinterpret_cast<f32x4*>(oblk + gf) = rv;
    }
}

extern "C" void kernel_launch(void* const* d_in, const int* in_sizes, int n_in,
                              void* d_out, int out_size, void* d_ws, size_t ws_size,
                              hipStream_t stream) {
    const float* x     = (const float*)d_in[0];
    // d_in[1] = proj: unused — Hadamard structure computed via FWHT
    const float* scale = (const float*)d_in[2];
    const float* bias  = (const float*)d_in[3];
    float* out = (float*)d_out;

    const int rows = in_sizes[0] / N_IN;            // 16384
    dim3 grid(rows / ROWS_PER_BLOCK), block(256);
    hipLaunchKernelGGL(fwht_proj_kernel, grid, block, 0, stream,
                       x, scale, bias, out);
}